// Round 18
// baseline (100.893 us; speedup 1.0000x reference)
//
#include <hip/hip_runtime.h>

typedef __bf16 bf16x8 __attribute__((ext_vector_type(8)));
typedef __bf16 bf16x4 __attribute__((ext_vector_type(4)));
typedef float f32x4 __attribute__((ext_vector_type(4)));
typedef short s16x4 __attribute__((ext_vector_type(4)));
typedef unsigned short u16;
typedef unsigned int u32;
typedef unsigned short u16x4 __attribute__((ext_vector_type(4)));
typedef unsigned short u16x8 __attribute__((ext_vector_type(8)));

#define AS1 __attribute__((address_space(1)))
#define AS3 __attribute__((address_space(3)))

__device__ __forceinline__ u16 f2bf(float f) {
  unsigned u = __builtin_bit_cast(unsigned, f);
  u += 0x7fffu + ((u >> 16) & 1u);
  return (u16)(u >> 16);
}

__device__ __forceinline__ float fast_exp2(float x) {
#if __has_builtin(__builtin_amdgcn_exp2f)
  return __builtin_amdgcn_exp2f(x);  // bare v_exp_f32
#else
  return exp2f(x);
#endif
}

__device__ __forceinline__ f32x4 mfma16(s16x4 a, s16x4 b, f32x4 c) {
#if __has_builtin(__builtin_amdgcn_mfma_f32_16x16x16bf16_1k)
  return __builtin_amdgcn_mfma_f32_16x16x16bf16_1k(a, b, c, 0, 0, 0);
#else
  asm("v_mfma_f32_16x16x16_bf16 %0, %1, %2, %0" : "+v"(c) : "v"(a), "v"(b));
  return c;
#endif
}

// ---------------- fp32 -> bf16 convert (x, w_qkv, w_fc fused) ----------------
__global__ __launch_bounds__(256) void cvt_all(const float* __restrict__ x,
                                               const float* __restrict__ wq,
                                               const float* __restrict__ wf,
                                               u16* __restrict__ xb, u16* __restrict__ wqb,
                                               u16* __restrict__ wfb) {
  long i = ((long)blockIdx.x * 256 + threadIdx.x) * 4;
  const float* src;
  u16* dst;
  long off;
  if (i < 4194304L) {
    src = x; dst = xb; off = i;
  } else if (i < 7340032L) {
    src = wq; dst = wqb; off = i - 4194304L;
  } else {
    src = wf; dst = wfb; off = i - 7340032L;
  }
  float4 v = *reinterpret_cast<const float4*>(src + off);
  u16x4 o;
  o.x = f2bf(v.x); o.y = f2bf(v.y); o.z = f2bf(v.z); o.w = f2bf(v.w);
  *reinterpret_cast<u16x4*>(dst + off) = o;
}

// -------- QKV GEMM: X[4096][1024] * W[3072][1024]^T, RMS fused, split outputs --------
// (r15 structure: BK=32 single-buffered -- measured local optimum.)
__global__ __launch_bounds__(256, 2) void gemm_qkv(const u16* __restrict__ A,
                                                   const u16* __restrict__ W,
                                                   u16* __restrict__ Qb,
                                                   u16* __restrict__ Kbf,
                                                   u16* __restrict__ vt,
                                                   const float* __restrict__ qw,
                                                   const float* __restrict__ kw) {
  constexpr int K = 1024;
  __shared__ __align__(16) u16 As[128 * 32];
  __shared__ __align__(16) u16 Bs[128 * 32];
  __shared__ __align__(16) u16 Ts[128 * 136];  // V transpose scratch (34 KB)
  const int tid = threadIdx.x;
  const int lane = tid & 63;
  const int wid = tid >> 6;
  const int wm = wid >> 1, wn = wid & 1;
  const int l16 = lane & 15, g4 = lane >> 4;
  const long bm = blockIdx.x, bn = blockIdx.y;

  const int srow = tid >> 2;
  const int scol = (tid & 3) * 8;
  const u16* aA0 = A + (bm * 128 + srow) * (long)K + scol;
  const u16* aA1 = aA0 + 64 * (long)K;
  const u16* aW0 = W + (bn * 128 + srow) * (long)K + scol;
  const u16* aW1 = aW0 + 64 * (long)K;

  f32x4 acc[4][4] = {};

  for (int kt = 0; kt < K; kt += 32) {
    __builtin_amdgcn_global_load_lds((AS1 void*)(aA0 + kt), (AS3 void*)(&As[tid * 8]), 16, 0, 0);
    __builtin_amdgcn_global_load_lds((AS1 void*)(aA1 + kt), (AS3 void*)(&As[2048 + tid * 8]), 16, 0, 0);
    __builtin_amdgcn_global_load_lds((AS1 void*)(aW0 + kt), (AS3 void*)(&Bs[tid * 8]), 16, 0, 0);
    __builtin_amdgcn_global_load_lds((AS1 void*)(aW1 + kt), (AS3 void*)(&Bs[2048 + tid * 8]), 16, 0, 0);
    __syncthreads();
    bf16x8 af[4], bfr[4];
#pragma unroll
    for (int m = 0; m < 4; ++m)
      af[m] = *reinterpret_cast<const bf16x8*>(&As[(wm * 64 + m * 16 + l16) * 32 + g4 * 8]);
#pragma unroll
    for (int n = 0; n < 4; ++n)
      bfr[n] = *reinterpret_cast<const bf16x8*>(&Bs[(wn * 64 + n * 16 + l16) * 32 + g4 * 8]);
#pragma unroll
    for (int m = 0; m < 4; ++m)
#pragma unroll
      for (int n = 0; n < 4; ++n)
        acc[m][n] = __builtin_amdgcn_mfma_f32_16x16x32_bf16(af[m], bfr[n], acc[m][n], 0, 0, 0);
    __syncthreads();
  }

  if (bn < 16) {
    // fused per-head RMSNorm for q (with attn scale) and k
    const float qscale = 0.18033688011112042f;  // 0.125 * log2(e)
    const float* w = (bn < 8) ? qw : kw;
    const float ws = (bn < 8) ? qscale : 1.0f;
    float wv[4];
#pragma unroll
    for (int n = 0; n < 4; ++n) wv[n] = w[n * 16 + l16] * ws;
#pragma unroll
    for (int m = 0; m < 4; ++m) {
#pragma unroll
      for (int j = 0; j < 4; ++j) {
        float ss = 0.f;
#pragma unroll
        for (int n = 0; n < 4; ++n) ss = fmaf(acc[m][n][j], acc[m][n][j], ss);
        ss += __shfl_xor(ss, 1);
        ss += __shfl_xor(ss, 2);
        ss += __shfl_xor(ss, 4);
        ss += __shfl_xor(ss, 8);
        const float inv = rsqrtf(ss * (1.0f / 64.0f) + 1e-5f);
#pragma unroll
        for (int n = 0; n < 4; ++n) acc[m][n][j] *= inv * wv[n];
      }
    }
    u16* dst = (bn < 8) ? Qb : Kbf;
    const long cb = (bn < 8) ? bn : (bn - 8);
#pragma unroll
    for (int m = 0; m < 4; ++m)
#pragma unroll
      for (int n = 0; n < 4; ++n)
#pragma unroll
        for (int j = 0; j < 4; ++j) {
          long row = bm * 128 + wm * 64 + m * 16 + g4 * 4 + j;
          long col = cb * 128 + wn * 64 + n * 16 + l16;
          dst[row * 1024 + col] = f2bf(acc[m][n][j]);
        }
  } else {
    // V: transpose via LDS, write vt[bh][d][key] coalesced
#pragma unroll
    for (int m = 0; m < 4; ++m)
#pragma unroll
      for (int n = 0; n < 4; ++n) {
        bf16x4 w4;
#pragma unroll
        for (int j = 0; j < 4; ++j) w4[j] = (__bf16)acc[m][n][j];
        const int lc = wn * 64 + n * 16 + l16;
        const int lr = wm * 64 + m * 16 + g4 * 4;
        *reinterpret_cast<bf16x4*>(&Ts[lc * 136 + lr]) = w4;
      }
    __syncthreads();
    const int b = (int)(bm >> 4);
    const int keybase = ((int)(bm & 15)) * 128;
#pragma unroll
    for (int u = 0; u < 2; ++u) {
      const int unit = u * 256 + tid;      // 0..511
      const int hh = unit >> 8;            // head half (2 heads per bn-block)
      const int d = (unit >> 2) & 63;
      const int kc = (unit & 3) * 32;
      const long bhv = b * 16 + (bn - 16) * 2 + hh;
      u16* dstp = vt + bhv * 131072L + (long)d * 2048 + keybase + kc;
      const u16* srcp = &Ts[(hh * 64 + d) * 136 + kc];
#pragma unroll
      for (int c = 0; c < 4; ++c)
        *reinterpret_cast<u16x8*>(dstp + c * 8) =
            *reinterpret_cast<const u16x8*>(srcp + c * 8);
    }
  }
}

// ---------------- FC GEMM: 128x64 tile, fp32 out (r15 single-buffered) ----------------
__global__ __launch_bounds__(256, 2) void gemm_fc(const u16* __restrict__ A,
                                                  const u16* __restrict__ W,
                                                  float* __restrict__ C) {
  constexpr int N = 1024, K = 1024;
  __shared__ __align__(16) u16 As[128 * 32];
  __shared__ __align__(16) u16 Bs[64 * 32];
  const int tid = threadIdx.x;
  const int lane = tid & 63;
  const int wid = tid >> 6;
  const int wm = wid >> 1, wn = wid & 1;
  const int l16 = lane & 15, g4 = lane >> 4;
  const long bm = blockIdx.x, bn = blockIdx.y;

  const int srow = tid >> 2;
  const int scol = (tid & 3) * 8;
  const u16* aA0 = A + (bm * 128 + srow) * (long)K + scol;
  const u16* aA1 = aA0 + 64 * (long)K;
  const u16* aW0 = W + (bn * 64 + srow) * (long)K + scol;

  f32x4 acc[4][2] = {};

  for (int kt = 0; kt < K; kt += 32) {
    __builtin_amdgcn_global_load_lds((AS1 void*)(aA0 + kt), (AS3 void*)(&As[tid * 8]), 16, 0, 0);
    __builtin_amdgcn_global_load_lds((AS1 void*)(aA1 + kt), (AS3 void*)(&As[2048 + tid * 8]), 16, 0, 0);
    __builtin_amdgcn_global_load_lds((AS1 void*)(aW0 + kt), (AS3 void*)(&Bs[tid * 8]), 16, 0, 0);
    __syncthreads();
    bf16x8 af[4], bfr[2];
#pragma unroll
    for (int m = 0; m < 4; ++m)
      af[m] = *reinterpret_cast<const bf16x8*>(&As[(wm * 64 + m * 16 + l16) * 32 + g4 * 8]);
#pragma unroll
    for (int n = 0; n < 2; ++n)
      bfr[n] = *reinterpret_cast<const bf16x8*>(&Bs[(wn * 32 + n * 16 + l16) * 32 + g4 * 8]);
#pragma unroll
    for (int m = 0; m < 4; ++m)
#pragma unroll
      for (int n = 0; n < 2; ++n)
        acc[m][n] = __builtin_amdgcn_mfma_f32_16x16x32_bf16(af[m], bfr[n], acc[m][n], 0, 0, 0);
    __syncthreads();
  }

#pragma unroll
  for (int m = 0; m < 4; ++m)
#pragma unroll
    for (int n = 0; n < 2; ++n)
#pragma unroll
      for (int j = 0; j < 4; ++j) {
        long row = bm * 128 + wm * 64 + m * 16 + g4 * 4 + j;
        long col = bn * 64 + wn * 32 + n * 16 + l16;
        C[row * N + col] = acc[m][n][j];
      }
}

// ---- causal flash attention: 2x2 wave split, P in registers, QK/PV software pipe ----
// Region i computes QK[i+1] (MFMA, K slot(i+1)) INTERLEAVED with softmax+PV[i]
// (VALU+MFMA, V slot(i)) -- independent, so exp2 chain hides under QK MFMAs.
// Stage at iter i: K[i+2]->slot(i) (K[i] dead), V[i+1]->slot(i+1) (V[i-1] dead);
// counted vmcnt(4) (K redundant-staged past the end to keep counts uniform).
__global__ __launch_bounds__(256, 4) void attn_causal(const u16* __restrict__ Qb,
                                                      const u16* __restrict__ Kbf,
                                                      const u16* __restrict__ vt,
                                                      u16* __restrict__ o) {
  __shared__ __align__(16) u16 SMEM[16384];  // K slots @0,@4096; V slots @8192,@12288

  const int tid = threadIdx.x, lane = tid & 63, wid = tid >> 6;
  const int l16 = lane & 15, g4 = lane >> 4;
  const int h8 = (l16 & 7) << 4;
  const int qh = wid & 1, kh = wid >> 1;

  const int f = blockIdx.x;
  const int xcd = f & 7;
  const int g = f >> 3;
  const int hb = g >> 5;
  const int w = g & 31;
  const int bh = xcd * 4 + hb;
  const int basei = (w & 1) ? (31 - (w >> 1)) : (w >> 1);
  const int it = (hb & 1) ? (31 - basei) : basei;  // q-tile index 0..31

  const long base = (long)(bh >> 4) * 2048 * 1024 + (bh & 15) * 64;
  const u16* qb = Qb + base;
  const u16* kb = Kbf + base;
  const u16* vtb = vt + (long)bh * 131072;

  f32x4 acc[2][4] = {};  // [qf][db]
  f32x4 lacc[2] = {};

  s16x4 ones4;
#pragma unroll
  for (int j = 0; j < 4; ++j) ones4[j] = (short)0x3F80;  // bf16 1.0

  const int krow = tid >> 3;                                      // 0..31
  const int scolE = (((tid & 7) * 16) ^ ((krow & 7) << 4)) >> 1;  // swizzled col (elems)

  auto stage_K = [&](int tile, int slot) {
    u16* KB = SMEM + slot * 4096;
    __builtin_amdgcn_global_load_lds((AS1 void*)(kb + (long)(tile * 64 + krow) * 1024 + scolE),
                                     (AS3 void*)(&KB[tid * 8]), 16, 0, 0);
    __builtin_amdgcn_global_load_lds((AS1 void*)(kb + (long)(tile * 64 + krow + 32) * 1024 + scolE),
                                     (AS3 void*)(&KB[2048 + tid * 8]), 16, 0, 0);
  };
  auto stage_V = [&](int tile, int slot) {
    u16* VB = SMEM + 8192 + slot * 4096;
    __builtin_amdgcn_global_load_lds((AS1 void*)(vtb + (long)krow * 2048 + tile * 64 + scolE),
                                     (AS3 void*)(&VB[tid * 8]), 16, 0, 0);
    __builtin_amdgcn_global_load_lds((AS1 void*)(vtb + (long)(krow + 32) * 2048 + tile * 64 + scolE),
                                     (AS3 void*)(&VB[2048 + tid * 8]), 16, 0, 0);
  };

  bf16x8 qv[2][2];

  // QK^T for tile j from K slot; writes s (S^T frag: lane q=l16, keys kf*16+g4*4+jj)
  auto qk_step = [&](f32x4 (&s)[2][2], int slot, bool diag) {
    if (diag && qh == 0 && kh == 1) {  // fully masked wave: exp2(-3e38)=0 downstream
#pragma unroll
      for (int kf = 0; kf < 2; ++kf)
#pragma unroll
        for (int qf = 0; qf < 2; ++qf)
#pragma unroll
          for (int j = 0; j < 4; ++j) s[kf][qf][j] = -3e38f;
      return;
    }
    const u16* KB = SMEM + slot * 4096;
    bf16x8 kfr[2][2];
#pragma unroll
    for (int kf = 0; kf < 2; ++kf) {
      const int row = kh * 32 + kf * 16 + l16;
#pragma unroll
      for (int ck = 0; ck < 2; ++ck)
        kfr[kf][ck] = *reinterpret_cast<const bf16x8*>(
            &KB[row * 64 + (((ck * 64 + g4 * 16) ^ h8) >> 1)]);
    }
    __builtin_amdgcn_s_setprio(1);
#pragma unroll
    for (int kf = 0; kf < 2; ++kf)
#pragma unroll
      for (int qf = 0; qf < 2; ++qf) {
        f32x4 z = {0.f, 0.f, 0.f, 0.f};
        z = __builtin_amdgcn_mfma_f32_16x16x32_bf16(kfr[kf][0], qv[qf][0], z, 0, 0, 0);
        z = __builtin_amdgcn_mfma_f32_16x16x32_bf16(kfr[kf][1], qv[qf][1], z, 0, 0, 0);
        s[kf][qf] = z;
      }
    __builtin_amdgcn_s_setprio(0);
    if (diag) {
#pragma unroll
      for (int kf = 0; kf < 2; ++kf)
#pragma unroll
        for (int qf = 0; qf < 2; ++qf) {
          const int keyl = kh * 32 + kf * 16 + g4 * 4;
          const int ql = qh * 32 + qf * 16 + l16;
#pragma unroll
          for (int j = 0; j < 4; ++j)
            if (keyl + j > ql) s[kf][qf][j] = -3e38f;
        }
    }
  };

  // softmax + l + PV for an S-tile, V from slot
  auto pv_step = [&](const f32x4 (&s)[2][2], int slot) {
    const u16* VB = SMEM + 8192 + slot * 4096;
    s16x4 pfr[2][2];
#pragma unroll
    for (int kf = 0; kf < 2; ++kf)
#pragma unroll
      for (int qf = 0; qf < 2; ++qf) {
        bf16x4 p;
#pragma unroll
        for (int j = 0; j < 4; ++j) p[j] = (__bf16)fast_exp2(s[kf][qf][j]);
        pfr[kf][qf] = __builtin_bit_cast(s16x4, p);
      }
    __builtin_amdgcn_s_setprio(1);
#pragma unroll
    for (int qf = 0; qf < 2; ++qf) {
      lacc[qf] = mfma16(pfr[0][qf], ones4, lacc[qf]);
      lacc[qf] = mfma16(pfr[1][qf], ones4, lacc[qf]);
    }
#pragma unroll
    for (int db = 0; db < 4; ++db) {
      const int vrow = db * 16 + l16;
#pragma unroll
      for (int kf = 0; kf < 2; ++kf) {
        const u16x4 vv = *reinterpret_cast<const u16x4*>(
            &VB[vrow * 64 + (((kh * 64 + kf * 32 + g4 * 8) ^ h8) >> 1)]);
        const s16x4 vf = __builtin_bit_cast(s16x4, vv);
#pragma unroll
        for (int qf = 0; qf < 2; ++qf) acc[qf][db] = mfma16(pfr[kf][qf], vf, acc[qf][db]);
      }
    }
    __builtin_amdgcn_s_setprio(0);
  };

  // ---- prologue: K[0],V[0] -> slot0; K[1] -> slot1 (K[0] again if it==0) ----
  stage_K(0, 0);
  stage_V(0, 0);
  stage_K(it >= 1 ? 1 : 0, 1);
  asm volatile("s_waitcnt vmcnt(2)" ::: "memory");  // K[0],V[0] landed; K[1] in flight
  __builtin_amdgcn_s_barrier();

  // Q hoist after the counted wait (keeps vmcnt accounting clean)
#pragma unroll
  for (int qf = 0; qf < 2; ++qf) {
    const u16* qp = qb + ((long)it * 64 + qh * 32 + qf * 16 + l16) * 1024;
    qv[qf][0] = *reinterpret_cast<const bf16x8*>(qp + g4 * 8);
    qv[qf][1] = *reinterpret_cast<const bf16x8*>(qp + 32 + g4 * 8);
  }

  f32x4 sA[2][2];
  qk_step(sA, 0, it == 0);

  for (int i = 0; i < it; ++i) {
    const int si = i & 1, sn = si ^ 1;
    stage_K(i + 2 <= it ? i + 2 : it, si);  // redundant past end keeps count uniform
    stage_V(i + 1, sn);
    asm volatile("s_waitcnt vmcnt(4)" ::: "memory");  // K[i+1], V[i] landed
    __builtin_amdgcn_s_barrier();
    f32x4 sB[2][2];
    qk_step(sB, sn, (i + 1) == it);  // QK[i+1] -- co-scheduled with pv_step below
    pv_step(sA, si);                 // softmax+PV of tile i
#pragma unroll
    for (int kf = 0; kf < 2; ++kf)
#pragma unroll
      for (int qf = 0; qf < 2; ++qf) sA[kf][qf] = sB[kf][qf];
    __builtin_amdgcn_s_barrier();
  }
  asm volatile("s_waitcnt vmcnt(0)" ::: "memory");
  __builtin_amdgcn_s_barrier();
  pv_step(sA, it & 1);  // final tile's softmax+PV
  __syncthreads();      // SMEM reused for combine

  // ---- combine the 2 kh-halves (additive thanks to static-max softmax) ----
  float* Ebuf = reinterpret_cast<float*>(SMEM);  // [2(qh)][32][68] f32 = 17408 B
  const int ebase = qh * 2176;
  if (kh == 1) {
#pragma unroll
    for (int qf = 0; qf < 2; ++qf) {
#pragma unroll
      for (int db = 0; db < 4; ++db)
#pragma unroll
        for (int j = 0; j < 4; ++j)
          Ebuf[ebase + (qf * 16 + g4 * 4 + j) * 68 + db * 16 + l16] = acc[qf][db][j];
      if (l16 == 0) {
#pragma unroll
        for (int j = 0; j < 4; ++j)
          Ebuf[ebase + (qf * 16 + g4 * 4 + j) * 68 + 64] = lacc[qf][j];
      }
    }
  }
  __syncthreads();
  if (kh == 0) {
    const long obase = (long)(bh >> 4) * 2048 * 1024 + (bh & 15) * 64;
#pragma unroll
    for (int qf = 0; qf < 2; ++qf) {
      float linv[4];
#pragma unroll
      for (int j = 0; j < 4; ++j) {
        const float lsum = lacc[qf][j] + Ebuf[ebase + (qf * 16 + g4 * 4 + j) * 68 + 64];
        linv[j] = 1.0f / lsum;
      }
#pragma unroll
      for (int db = 0; db < 4; ++db)
#pragma unroll
        for (int j = 0; j < 4; ++j) {
          const int row = qh * 32 + qf * 16 + g4 * 4 + j;
          const float v =
              acc[qf][db][j] + Ebuf[ebase + (qf * 16 + g4 * 4 + j) * 68 + db * 16 + l16];
          o[obase + ((long)it * 64 + row) * 1024 + db * 16 + l16] = f2bf(v * linv[j]);
        }
    }
  }
}

extern "C" void kernel_launch(void* const* d_in, const int* in_sizes, int n_in,
                              void* d_out, int out_size, void* d_ws, size_t ws_size,
                              hipStream_t stream) {
  const float* x = (const float*)d_in[0];
  // d_in[1] = mask (causal tril -- not needed)
  const float* w_qkv = (const float*)d_in[2];
  const float* w_fc = (const float*)d_in[3];
  const float* qw = (const float*)d_in[4];
  const float* kw = (const float*)d_in[5];
  // d_in[6] = subset_attention_size: with a causal mask the split is an identity.
  float* out = (float*)d_out;

  char* ws = (char*)d_ws;
  u16* xb    = (u16*)(ws);                   // 8 MB
  u16* wqkvb = (u16*)(ws + (8L << 20));      // 6 MB
  u16* wfcb  = (u16*)(ws + (14L << 20));     // 2 MB
  u16* Qb    = (u16*)(ws + (16L << 20));     // 8 MB
  u16* Kbf   = (u16*)(ws + (24L << 20));     // 8 MB
  u16* vt    = (u16*)(ws + (32L << 20));     // 8 MB
  u16* ob    = (u16*)(ws + (40L << 20));     // 8 MB

  cvt_all<<<8192, 256, 0, stream>>>(x, w_qkv, w_fc, xb, wqkvb, wfcb);
  gemm_qkv<<<dim3(32, 24), 256, 0, stream>>>(xb, wqkvb, Qb, Kbf, vt, qw, kw);
  attn_causal<<<1024, 256, 0, stream>>>(Qb, Kbf, vt, ob);
  gemm_fc<<<dim3(32, 16), 256, 0, stream>>>(ob, wfcb, out);
}

// Round 19
// 98.074 us; speedup vs baseline: 1.0287x; 1.0287x over previous
//
#include <hip/hip_runtime.h>

typedef __bf16 bf16x8 __attribute__((ext_vector_type(8)));
typedef __bf16 bf16x4 __attribute__((ext_vector_type(4)));
typedef float f32x4 __attribute__((ext_vector_type(4)));
typedef short s16x4 __attribute__((ext_vector_type(4)));
typedef unsigned short u16;
typedef unsigned int u32;
typedef unsigned short u16x4 __attribute__((ext_vector_type(4)));
typedef unsigned short u16x8 __attribute__((ext_vector_type(8)));

#define AS1 __attribute__((address_space(1)))
#define AS3 __attribute__((address_space(3)))

__device__ __forceinline__ u16 f2bf(float f) {
  unsigned u = __builtin_bit_cast(unsigned, f);
  u += 0x7fffu + ((u >> 16) & 1u);
  return (u16)(u >> 16);
}

__device__ __forceinline__ float fast_exp2(float x) {
#if __has_builtin(__builtin_amdgcn_exp2f)
  return __builtin_amdgcn_exp2f(x);  // bare v_exp_f32
#else
  return exp2f(x);
#endif
}

__device__ __forceinline__ f32x4 mfma16(s16x4 a, s16x4 b, f32x4 c) {
#if __has_builtin(__builtin_amdgcn_mfma_f32_16x16x16bf16_1k)
  return __builtin_amdgcn_mfma_f32_16x16x16bf16_1k(a, b, c, 0, 0, 0);
#else
  asm("v_mfma_f32_16x16x16_bf16 %0, %1, %2, %0" : "+v"(c) : "v"(a), "v"(b));
  return c;
#endif
}

// ---------------- fp32 -> bf16 convert (x, w_qkv, w_fc fused) ----------------
__global__ __launch_bounds__(256) void cvt_all(const float* __restrict__ x,
                                               const float* __restrict__ wq,
                                               const float* __restrict__ wf,
                                               u16* __restrict__ xb, u16* __restrict__ wqb,
                                               u16* __restrict__ wfb) {
  long i = ((long)blockIdx.x * 256 + threadIdx.x) * 4;
  const float* src;
  u16* dst;
  long off;
  if (i < 4194304L) {
    src = x; dst = xb; off = i;
  } else if (i < 7340032L) {
    src = wq; dst = wqb; off = i - 4194304L;
  } else {
    src = wf; dst = wfb; off = i - 7340032L;
  }
  float4 v = *reinterpret_cast<const float4*>(src + off);
  u16x4 o;
  o.x = f2bf(v.x); o.y = f2bf(v.y); o.z = f2bf(v.z); o.w = f2bf(v.w);
  *reinterpret_cast<u16x4*>(dst + off) = o;
}

// -------- QKV GEMM: X[4096][1024] * W[3072][1024]^T, RMS fused, split outputs --------
// (r15 structure: BK=32 single-buffered -- measured local optimum across dbuf (r11,
// r16) and BK=64 (r13/14) experiments.)
// bn<8 -> Qbuf (RMS, pre-scaled by 0.125*log2e); 8<=bn<16 -> Kbuf (RMS);
// bn>=16 -> V written TRANSPOSED to vt[bh][d=64][key=2048] via LDS.
__global__ __launch_bounds__(256, 2) void gemm_qkv(const u16* __restrict__ A,
                                                   const u16* __restrict__ W,
                                                   u16* __restrict__ Qb,
                                                   u16* __restrict__ Kbf,
                                                   u16* __restrict__ vt,
                                                   const float* __restrict__ qw,
                                                   const float* __restrict__ kw) {
  constexpr int K = 1024;
  __shared__ __align__(16) u16 As[128 * 32];
  __shared__ __align__(16) u16 Bs[128 * 32];
  __shared__ __align__(16) u16 Ts[128 * 136];  // V transpose scratch (34 KB)
  const int tid = threadIdx.x;
  const int lane = tid & 63;
  const int wid = tid >> 6;
  const int wm = wid >> 1, wn = wid & 1;
  const int l16 = lane & 15, g4 = lane >> 4;
  const long bm = blockIdx.x, bn = blockIdx.y;

  const int srow = tid >> 2;
  const int scol = (tid & 3) * 8;
  const u16* aA0 = A + (bm * 128 + srow) * (long)K + scol;
  const u16* aA1 = aA0 + 64 * (long)K;
  const u16* aW0 = W + (bn * 128 + srow) * (long)K + scol;
  const u16* aW1 = aW0 + 64 * (long)K;

  f32x4 acc[4][4] = {};

  for (int kt = 0; kt < K; kt += 32) {
    __builtin_amdgcn_global_load_lds((AS1 void*)(aA0 + kt), (AS3 void*)(&As[tid * 8]), 16, 0, 0);
    __builtin_amdgcn_global_load_lds((AS1 void*)(aA1 + kt), (AS3 void*)(&As[2048 + tid * 8]), 16, 0, 0);
    __builtin_amdgcn_global_load_lds((AS1 void*)(aW0 + kt), (AS3 void*)(&Bs[tid * 8]), 16, 0, 0);
    __builtin_amdgcn_global_load_lds((AS1 void*)(aW1 + kt), (AS3 void*)(&Bs[2048 + tid * 8]), 16, 0, 0);
    __syncthreads();
    bf16x8 af[4], bfr[4];
#pragma unroll
    for (int m = 0; m < 4; ++m)
      af[m] = *reinterpret_cast<const bf16x8*>(&As[(wm * 64 + m * 16 + l16) * 32 + g4 * 8]);
#pragma unroll
    for (int n = 0; n < 4; ++n)
      bfr[n] = *reinterpret_cast<const bf16x8*>(&Bs[(wn * 64 + n * 16 + l16) * 32 + g4 * 8]);
#pragma unroll
    for (int m = 0; m < 4; ++m)
#pragma unroll
      for (int n = 0; n < 4; ++n)
        acc[m][n] = __builtin_amdgcn_mfma_f32_16x16x32_bf16(af[m], bfr[n], acc[m][n], 0, 0, 0);
    __syncthreads();
  }

  if (bn < 16) {
    // fused per-head RMSNorm for q (with attn scale) and k
    const float qscale = 0.18033688011112042f;  // 0.125 * log2(e)
    const float* w = (bn < 8) ? qw : kw;
    const float ws = (bn < 8) ? qscale : 1.0f;
    float wv[4];
#pragma unroll
    for (int n = 0; n < 4; ++n) wv[n] = w[n * 16 + l16] * ws;
#pragma unroll
    for (int m = 0; m < 4; ++m) {
#pragma unroll
      for (int j = 0; j < 4; ++j) {
        float ss = 0.f;
#pragma unroll
        for (int n = 0; n < 4; ++n) ss = fmaf(acc[m][n][j], acc[m][n][j], ss);
        ss += __shfl_xor(ss, 1);
        ss += __shfl_xor(ss, 2);
        ss += __shfl_xor(ss, 4);
        ss += __shfl_xor(ss, 8);
        const float inv = rsqrtf(ss * (1.0f / 64.0f) + 1e-5f);
#pragma unroll
        for (int n = 0; n < 4; ++n) acc[m][n][j] *= inv * wv[n];
      }
    }
    u16* dst = (bn < 8) ? Qb : Kbf;
    const long cb = (bn < 8) ? bn : (bn - 8);
#pragma unroll
    for (int m = 0; m < 4; ++m)
#pragma unroll
      for (int n = 0; n < 4; ++n)
#pragma unroll
        for (int j = 0; j < 4; ++j) {
          long row = bm * 128 + wm * 64 + m * 16 + g4 * 4 + j;
          long col = cb * 128 + wn * 64 + n * 16 + l16;
          dst[row * 1024 + col] = f2bf(acc[m][n][j]);
        }
  } else {
    // V: transpose via LDS, write vt[bh][d][key] coalesced
#pragma unroll
    for (int m = 0; m < 4; ++m)
#pragma unroll
      for (int n = 0; n < 4; ++n) {
        bf16x4 w4;
#pragma unroll
        for (int j = 0; j < 4; ++j) w4[j] = (__bf16)acc[m][n][j];
        const int lc = wn * 64 + n * 16 + l16;
        const int lr = wm * 64 + m * 16 + g4 * 4;
        *reinterpret_cast<bf16x4*>(&Ts[lc * 136 + lr]) = w4;
      }
    __syncthreads();
    const int b = (int)(bm >> 4);
    const int keybase = ((int)(bm & 15)) * 128;
#pragma unroll
    for (int u = 0; u < 2; ++u) {
      const int unit = u * 256 + tid;      // 0..511
      const int hh = unit >> 8;            // head half (2 heads per bn-block)
      const int d = (unit >> 2) & 63;
      const int kc = (unit & 3) * 32;
      const long bhv = b * 16 + (bn - 16) * 2 + hh;
      u16* dstp = vt + bhv * 131072L + (long)d * 2048 + keybase + kc;
      const u16* srcp = &Ts[(hh * 64 + d) * 136 + kc];
#pragma unroll
      for (int c = 0; c < 4; ++c)
        *reinterpret_cast<u16x8*>(dstp + c * 8) =
            *reinterpret_cast<const u16x8*>(srcp + c * 8);
    }
  }
}

// ---------------- FC GEMM: 128x64 tile, fp32 out (r15 single-buffered) ----------------
__global__ __launch_bounds__(256, 2) void gemm_fc(const u16* __restrict__ A,
                                                  const u16* __restrict__ W,
                                                  float* __restrict__ C) {
  constexpr int N = 1024, K = 1024;
  __shared__ __align__(16) u16 As[128 * 32];
  __shared__ __align__(16) u16 Bs[64 * 32];
  const int tid = threadIdx.x;
  const int lane = tid & 63;
  const int wid = tid >> 6;
  const int wm = wid >> 1, wn = wid & 1;
  const int l16 = lane & 15, g4 = lane >> 4;
  const long bm = blockIdx.x, bn = blockIdx.y;

  const int srow = tid >> 2;
  const int scol = (tid & 3) * 8;
  const u16* aA0 = A + (bm * 128 + srow) * (long)K + scol;
  const u16* aA1 = aA0 + 64 * (long)K;
  const u16* aW0 = W + (bn * 64 + srow) * (long)K + scol;

  f32x4 acc[4][2] = {};

  for (int kt = 0; kt < K; kt += 32) {
    __builtin_amdgcn_global_load_lds((AS1 void*)(aA0 + kt), (AS3 void*)(&As[tid * 8]), 16, 0, 0);
    __builtin_amdgcn_global_load_lds((AS1 void*)(aA1 + kt), (AS3 void*)(&As[2048 + tid * 8]), 16, 0, 0);
    __builtin_amdgcn_global_load_lds((AS1 void*)(aW0 + kt), (AS3 void*)(&Bs[tid * 8]), 16, 0, 0);
    __syncthreads();
    bf16x8 af[4], bfr[2];
#pragma unroll
    for (int m = 0; m < 4; ++m)
      af[m] = *reinterpret_cast<const bf16x8*>(&As[(wm * 64 + m * 16 + l16) * 32 + g4 * 8]);
#pragma unroll
    for (int n = 0; n < 2; ++n)
      bfr[n] = *reinterpret_cast<const bf16x8*>(&Bs[(wn * 32 + n * 16 + l16) * 32 + g4 * 8]);
#pragma unroll
    for (int m = 0; m < 4; ++m)
#pragma unroll
      for (int n = 0; n < 2; ++n)
        acc[m][n] = __builtin_amdgcn_mfma_f32_16x16x32_bf16(af[m], bfr[n], acc[m][n], 0, 0, 0);
    __syncthreads();
  }

#pragma unroll
  for (int m = 0; m < 4; ++m)
#pragma unroll
    for (int n = 0; n < 2; ++n)
#pragma unroll
      for (int j = 0; j < 4; ++j) {
        long row = bm * 128 + wm * 64 + m * 16 + g4 * 4 + j;
        long col = bn * 64 + wn * 32 + n * 16 + l16;
        C[row * N + col] = acc[m][n][j];
      }
}

// ---- causal flash attention: 2x2 wave split (qh x kh), P stays in registers --------
// (r9/r15 structure + fast_exp2 -- best measured: ~39 us, MfmaUtil ~25%.)
__global__ __launch_bounds__(256, 4) void attn_causal(const u16* __restrict__ Qb,
                                                      const u16* __restrict__ Kbf,
                                                      const u16* __restrict__ vt,
                                                      u16* __restrict__ o) {
  __shared__ __align__(16) u16 SMEM[16384];  // 32 KB: K dbuf (16 KB) + V dbuf (16 KB)

  const int tid = threadIdx.x, lane = tid & 63, wid = tid >> 6;
  const int l16 = lane & 15, g4 = lane >> 4;
  const int h8 = (l16 & 7) << 4;
  const int qh = wid & 1, kh = wid >> 1;

  const int f = blockIdx.x;
  const int xcd = f & 7;
  const int g = f >> 3;
  const int hb = g >> 5;
  const int w = g & 31;
  const int bh = xcd * 4 + hb;
  const int basei = (w & 1) ? (31 - (w >> 1)) : (w >> 1);
  const int it = (hb & 1) ? (31 - basei) : basei;  // q-tile index 0..31

  const long base = (long)(bh >> 4) * 2048 * 1024 + (bh & 15) * 64;
  const u16* qb = Qb + base;
  const u16* kb = Kbf + base;
  const u16* vtb = vt + (long)bh * 131072;

  // Q hoist: rows it*64 + qh*32 + qf*16 + l16 (B-operand of QK mfma32)
  bf16x8 qv[2][2];
#pragma unroll
  for (int qf = 0; qf < 2; ++qf) {
    const u16* qp = qb + ((long)it * 64 + qh * 32 + qf * 16 + l16) * 1024;
    qv[qf][0] = *reinterpret_cast<const bf16x8*>(qp + g4 * 8);
    qv[qf][1] = *reinterpret_cast<const bf16x8*>(qp + 32 + g4 * 8);
  }

  f32x4 acc[2][4] = {};  // [qf][db]: row q = qf*16+g4*4+j (local), col d = db*16+l16
  f32x4 lacc[2] = {};    // [qf]: l for q = qf*16+g4*4+j

  s16x4 ones4;
#pragma unroll
  for (int j = 0; j < 4; ++j) ones4[j] = (short)0x3F80;  // bf16 1.0

  const int krow = tid >> 3;                                      // 0..31
  const int scolE = (((tid & 7) * 16) ^ ((krow & 7) << 4)) >> 1;  // swizzled col (elems)

  auto stage_issue = [&](int buf, int kt) {
    u16* KB = SMEM + buf * 4096;
    u16* VB = SMEM + 8192 + buf * 4096;
    __builtin_amdgcn_global_load_lds((AS1 void*)(kb + (long)(kt * 64 + krow) * 1024 + scolE),
                                     (AS3 void*)(&KB[tid * 8]), 16, 0, 0);
    __builtin_amdgcn_global_load_lds((AS1 void*)(kb + (long)(kt * 64 + krow + 32) * 1024 + scolE),
                                     (AS3 void*)(&KB[2048 + tid * 8]), 16, 0, 0);
    __builtin_amdgcn_global_load_lds((AS1 void*)(vtb + (long)krow * 2048 + kt * 64 + scolE),
                                     (AS3 void*)(&VB[tid * 8]), 16, 0, 0);
    __builtin_amdgcn_global_load_lds((AS1 void*)(vtb + (long)(krow + 32) * 2048 + kt * 64 + scolE),
                                     (AS3 void*)(&VB[2048 + tid * 8]), 16, 0, 0);
  };

  auto tile_step = [&](int cur, bool diag) {
    if (diag && qh == 0 && kh == 1) return;  // fully masked sub-block (wave-uniform)
    const u16* KB = SMEM + cur * 4096;
    const u16* VB = SMEM + 8192 + cur * 4096;
    // K A-frags: rows = wave's keys kh*32 + kf*16 + l16
    bf16x8 kfr[2][2];
#pragma unroll
    for (int kf = 0; kf < 2; ++kf) {
      const int row = kh * 32 + kf * 16 + l16;
#pragma unroll
      for (int ck = 0; ck < 2; ++ck)
        kfr[kf][ck] = *reinterpret_cast<const bf16x8*>(
            &KB[row * 64 + (((ck * 64 + g4 * 16) ^ h8) >> 1)]);
    }
    // S^T[key][q]: lane holds q = l16, keys = kf*16 + g4*4 + j (within wave's 32)
    f32x4 s[2][2];
    __builtin_amdgcn_s_setprio(1);
#pragma unroll
    for (int kf = 0; kf < 2; ++kf)
#pragma unroll
      for (int qf = 0; qf < 2; ++qf) {
        f32x4 z = {0.f, 0.f, 0.f, 0.f};
        z = __builtin_amdgcn_mfma_f32_16x16x32_bf16(kfr[kf][0], qv[qf][0], z, 0, 0, 0);
        z = __builtin_amdgcn_mfma_f32_16x16x32_bf16(kfr[kf][1], qv[qf][1], z, 0, 0, 0);
        s[kf][qf] = z;
      }
    __builtin_amdgcn_s_setprio(0);
    if (diag) {
#pragma unroll
      for (int kf = 0; kf < 2; ++kf)
#pragma unroll
        for (int qf = 0; qf < 2; ++qf) {
          const int keyl = kh * 32 + kf * 16 + g4 * 4;
          const int ql = qh * 32 + qf * 16 + l16;
#pragma unroll
          for (int j = 0; j < 4; ++j)
            if (keyl + j > ql) s[kf][qf][j] = -3e38f;
        }
    }
    // exp2 + pack to PV A-frags (zero data movement)
    s16x4 pfr[2][2];
#pragma unroll
    for (int kf = 0; kf < 2; ++kf)
#pragma unroll
      for (int qf = 0; qf < 2; ++qf) {
        bf16x4 p;
#pragma unroll
        for (int j = 0; j < 4; ++j) p[j] = (__bf16)fast_exp2(s[kf][qf][j]);
        pfr[kf][qf] = __builtin_bit_cast(s16x4, p);
      }
    __builtin_amdgcn_s_setprio(1);
#pragma unroll
    for (int qf = 0; qf < 2; ++qf) {
      lacc[qf] = mfma16(pfr[0][qf], ones4, lacc[qf]);
      lacc[qf] = mfma16(pfr[1][qf], ones4, lacc[qf]);
    }
    // PV: B-frag = V^T at (row d = db*16+l16, keys kh*64+kf*32+g4*8 bytes)
#pragma unroll
    for (int db = 0; db < 4; ++db) {
      const int vrow = db * 16 + l16;
#pragma unroll
      for (int kf = 0; kf < 2; ++kf) {
        const u16x4 vv = *reinterpret_cast<const u16x4*>(
            &VB[vrow * 64 + (((kh * 64 + kf * 32 + g4 * 8) ^ h8) >> 1)]);
        const s16x4 vf = __builtin_bit_cast(s16x4, vv);
#pragma unroll
        for (int qf = 0; qf < 2; ++qf) acc[qf][db] = mfma16(pfr[kf][qf], vf, acc[qf][db]);
      }
    }
    __builtin_amdgcn_s_setprio(0);
  };

  stage_issue(0, 0);
  __syncthreads();

  for (int kt = 0; kt < it; ++kt) {
    const int cur = kt & 1;
    stage_issue(cur ^ 1, kt + 1);
    tile_step(cur, false);
    __syncthreads();
  }
  tile_step(it & 1, true);  // diagonal tile
  __syncthreads();          // tiles done; SMEM reused for combine

  // ---- combine the 2 kh-halves (additive thanks to static-max softmax) ----
  float* Ebuf = reinterpret_cast<float*>(SMEM);  // [2(qh)][32][68] f32 = 17408 B
  const int ebase = qh * 2176;
  if (kh == 1) {
#pragma unroll
    for (int qf = 0; qf < 2; ++qf) {
#pragma unroll
      for (int db = 0; db < 4; ++db)
#pragma unroll
        for (int j = 0; j < 4; ++j)
          Ebuf[ebase + (qf * 16 + g4 * 4 + j) * 68 + db * 16 + l16] = acc[qf][db][j];
      if (l16 == 0) {
#pragma unroll
        for (int j = 0; j < 4; ++j)
          Ebuf[ebase + (qf * 16 + g4 * 4 + j) * 68 + 64] = lacc[qf][j];
      }
    }
  }
  __syncthreads();
  if (kh == 0) {
    const long obase = (long)(bh >> 4) * 2048 * 1024 + (bh & 15) * 64;
#pragma unroll
    for (int qf = 0; qf < 2; ++qf) {
      float linv[4];
#pragma unroll
      for (int j = 0; j < 4; ++j) {
        const float lsum = lacc[qf][j] + Ebuf[ebase + (qf * 16 + g4 * 4 + j) * 68 + 64];
        linv[j] = 1.0f / lsum;
      }
#pragma unroll
      for (int db = 0; db < 4; ++db)
#pragma unroll
        for (int j = 0; j < 4; ++j) {
          const int row = qh * 32 + qf * 16 + g4 * 4 + j;
          const float v =
              acc[qf][db][j] + Ebuf[ebase + (qf * 16 + g4 * 4 + j) * 68 + db * 16 + l16];
          o[obase + ((long)it * 64 + row) * 1024 + db * 16 + l16] = f2bf(v * linv[j]);
        }
    }
  }
}

extern "C" void kernel_launch(void* const* d_in, const int* in_sizes, int n_in,
                              void* d_out, int out_size, void* d_ws, size_t ws_size,
                              hipStream_t stream) {
  const float* x = (const float*)d_in[0];
  // d_in[1] = mask (causal tril -- not needed)
  const float* w_qkv = (const float*)d_in[2];
  const float* w_fc = (const float*)d_in[3];
  const float* qw = (const float*)d_in[4];
  const float* kw = (const float*)d_in[5];
  // d_in[6] = subset_attention_size: with a causal mask the split is an identity.
  float* out = (float*)d_out;

  char* ws = (char*)d_ws;
  u16* xb    = (u16*)(ws);                   // 8 MB
  u16* wqkvb = (u16*)(ws + (8L << 20));      // 6 MB
  u16* wfcb  = (u16*)(ws + (14L << 20));     // 2 MB
  u16* Qb    = (u16*)(ws + (16L << 20));     // 8 MB
  u16* Kbf   = (u16*)(ws + (24L << 20));     // 8 MB
  u16* vt    = (u16*)(ws + (32L << 20));     // 8 MB
  u16* ob    = (u16*)(ws + (40L << 20));     // 8 MB

  cvt_all<<<8192, 256, 0, stream>>>(x, w_qkv, w_fc, xb, wqkvb, wfcb);
  gemm_qkv<<<dim3(32, 24), 256, 0, stream>>>(xb, wqkvb, Qb, Kbf, vt, qw, kw);
  attn_causal<<<1024, 256, 0, stream>>>(Qb, Kbf, vt, ob);
  gemm_fc<<<dim3(32, 16), 256, 0, stream>>>(ob, wfcb, out);
}

// Round 20
// 97.004 us; speedup vs baseline: 1.0401x; 1.0110x over previous
//
#include <hip/hip_runtime.h>

typedef __bf16 bf16x8 __attribute__((ext_vector_type(8)));
typedef __bf16 bf16x4 __attribute__((ext_vector_type(4)));
typedef float f32x4 __attribute__((ext_vector_type(4)));
typedef short s16x4 __attribute__((ext_vector_type(4)));
typedef unsigned short u16;
typedef unsigned int u32;
typedef unsigned short u16x4 __attribute__((ext_vector_type(4)));
typedef unsigned short u16x8 __attribute__((ext_vector_type(8)));

#define AS1 __attribute__((address_space(1)))
#define AS3 __attribute__((address_space(3)))

__device__ __forceinline__ u16 f2bf(float f) {
  unsigned u = __builtin_bit_cast(unsigned, f);
  u += 0x7fffu + ((u >> 16) & 1u);
  return (u16)(u >> 16);
}

__device__ __forceinline__ float fast_exp2(float x) {
#if __has_builtin(__builtin_amdgcn_exp2f)
  return __builtin_amdgcn_exp2f(x);  // bare v_exp_f32
#else
  return exp2f(x);
#endif
}

__device__ __forceinline__ f32x4 mfma16(s16x4 a, s16x4 b, f32x4 c) {
#if __has_builtin(__builtin_amdgcn_mfma_f32_16x16x16bf16_1k)
  return __builtin_amdgcn_mfma_f32_16x16x16bf16_1k(a, b, c, 0, 0, 0);
#else
  asm("v_mfma_f32_16x16x16_bf16 %0, %1, %2, %0" : "+v"(c) : "v"(a), "v"(b));
  return c;
#endif
}

// ---------------- fp32 -> bf16 convert (x, w_qkv, w_fc fused) ----------------
__global__ __launch_bounds__(256) void cvt_all(const float* __restrict__ x,
                                               const float* __restrict__ wq,
                                               const float* __restrict__ wf,
                                               u16* __restrict__ xb, u16* __restrict__ wqb,
                                               u16* __restrict__ wfb) {
  long i = ((long)blockIdx.x * 256 + threadIdx.x) * 4;
  const float* src;
  u16* dst;
  long off;
  if (i < 4194304L) {
    src = x; dst = xb; off = i;
  } else if (i < 7340032L) {
    src = wq; dst = wqb; off = i - 4194304L;
  } else {
    src = wf; dst = wfb; off = i - 7340032L;
  }
  float4 v = *reinterpret_cast<const float4*>(src + off);
  u16x4 o;
  o.x = f2bf(v.x); o.y = f2bf(v.y); o.z = f2bf(v.z); o.w = f2bf(v.w);
  *reinterpret_cast<u16x4*>(dst + off) = o;
}

// -------- QKV GEMM: X[4096][1024] * W[3072][1024]^T, RMS fused, split outputs --------
// r15 structure + LDS XOR swizzle for the [128][32] (64 B row) tiles:
// byte_in_row ^= ((row>>1)&3)<<4 -- maps the 16-row b128 fragment read to 8 disjoint
// bank-quads (2-way aliasing = free, was 8-way = 2.94x). Applied via pre-swizzled
// global source (staging) + XOR'd read address. Invariant under +8/+16/+64 row shifts.
__global__ __launch_bounds__(256, 2) void gemm_qkv(const u16* __restrict__ A,
                                                   const u16* __restrict__ W,
                                                   u16* __restrict__ Qb,
                                                   u16* __restrict__ Kbf,
                                                   u16* __restrict__ vt,
                                                   const float* __restrict__ qw,
                                                   const float* __restrict__ kw) {
  constexpr int K = 1024;
  __shared__ __align__(16) u16 As[128 * 32];
  __shared__ __align__(16) u16 Bs[128 * 32];
  __shared__ __align__(16) u16 Ts[128 * 136];  // V transpose scratch (34 KB)
  const int tid = threadIdx.x;
  const int lane = tid & 63;
  const int wid = tid >> 6;
  const int wm = wid >> 1, wn = wid & 1;
  const int l16 = lane & 15, g4 = lane >> 4;
  const int h4 = ((l16 >> 1) & 3) << 4;  // read-side XOR for rows == l16 (mod 16)
  const long bm = blockIdx.x, bn = blockIdx.y;

  const int srow = tid >> 2;                                          // 0..63
  const int scolE = (((tid & 3) * 16) ^ (((srow >> 1) & 3) << 4)) >> 1;  // swizzled src col
  const u16* aA0 = A + (bm * 128 + srow) * (long)K + scolE;
  const u16* aA1 = aA0 + 64 * (long)K;
  const u16* aW0 = W + (bn * 128 + srow) * (long)K + scolE;
  const u16* aW1 = aW0 + 64 * (long)K;

  f32x4 acc[4][4] = {};

  for (int kt = 0; kt < K; kt += 32) {
    __builtin_amdgcn_global_load_lds((AS1 void*)(aA0 + kt), (AS3 void*)(&As[tid * 8]), 16, 0, 0);
    __builtin_amdgcn_global_load_lds((AS1 void*)(aA1 + kt), (AS3 void*)(&As[2048 + tid * 8]), 16, 0, 0);
    __builtin_amdgcn_global_load_lds((AS1 void*)(aW0 + kt), (AS3 void*)(&Bs[tid * 8]), 16, 0, 0);
    __builtin_amdgcn_global_load_lds((AS1 void*)(aW1 + kt), (AS3 void*)(&Bs[2048 + tid * 8]), 16, 0, 0);
    __syncthreads();
    bf16x8 af[4], bfr[4];
#pragma unroll
    for (int m = 0; m < 4; ++m)
      af[m] = *reinterpret_cast<const bf16x8*>(
          &As[(wm * 64 + m * 16 + l16) * 32 + (((g4 * 16) ^ h4) >> 1)]);
#pragma unroll
    for (int n = 0; n < 4; ++n)
      bfr[n] = *reinterpret_cast<const bf16x8*>(
          &Bs[(wn * 64 + n * 16 + l16) * 32 + (((g4 * 16) ^ h4) >> 1)]);
#pragma unroll
    for (int m = 0; m < 4; ++m)
#pragma unroll
      for (int n = 0; n < 4; ++n)
        acc[m][n] = __builtin_amdgcn_mfma_f32_16x16x32_bf16(af[m], bfr[n], acc[m][n], 0, 0, 0);
    __syncthreads();
  }

  if (bn < 16) {
    // fused per-head RMSNorm for q (with attn scale) and k
    const float qscale = 0.18033688011112042f;  // 0.125 * log2(e)
    const float* w = (bn < 8) ? qw : kw;
    const float ws = (bn < 8) ? qscale : 1.0f;
    float wv[4];
#pragma unroll
    for (int n = 0; n < 4; ++n) wv[n] = w[n * 16 + l16] * ws;
#pragma unroll
    for (int m = 0; m < 4; ++m) {
#pragma unroll
      for (int j = 0; j < 4; ++j) {
        float ss = 0.f;
#pragma unroll
        for (int n = 0; n < 4; ++n) ss = fmaf(acc[m][n][j], acc[m][n][j], ss);
        ss += __shfl_xor(ss, 1);
        ss += __shfl_xor(ss, 2);
        ss += __shfl_xor(ss, 4);
        ss += __shfl_xor(ss, 8);
        const float inv = rsqrtf(ss * (1.0f / 64.0f) + 1e-5f);
#pragma unroll
        for (int n = 0; n < 4; ++n) acc[m][n][j] *= inv * wv[n];
      }
    }
    u16* dst = (bn < 8) ? Qb : Kbf;
    const long cb = (bn < 8) ? bn : (bn - 8);
#pragma unroll
    for (int m = 0; m < 4; ++m)
#pragma unroll
      for (int n = 0; n < 4; ++n)
#pragma unroll
        for (int j = 0; j < 4; ++j) {
          long row = bm * 128 + wm * 64 + m * 16 + g4 * 4 + j;
          long col = cb * 128 + wn * 64 + n * 16 + l16;
          dst[row * 1024 + col] = f2bf(acc[m][n][j]);
        }
  } else {
    // V: transpose via LDS, write vt[bh][d][key] coalesced
#pragma unroll
    for (int m = 0; m < 4; ++m)
#pragma unroll
      for (int n = 0; n < 4; ++n) {
        bf16x4 w4;
#pragma unroll
        for (int j = 0; j < 4; ++j) w4[j] = (__bf16)acc[m][n][j];
        const int lc = wn * 64 + n * 16 + l16;
        const int lr = wm * 64 + m * 16 + g4 * 4;
        *reinterpret_cast<bf16x4*>(&Ts[lc * 136 + lr]) = w4;
      }
    __syncthreads();
    const int b = (int)(bm >> 4);
    const int keybase = ((int)(bm & 15)) * 128;
#pragma unroll
    for (int u = 0; u < 2; ++u) {
      const int unit = u * 256 + tid;      // 0..511
      const int hh = unit >> 8;            // head half (2 heads per bn-block)
      const int d = (unit >> 2) & 63;
      const int kc = (unit & 3) * 32;
      const long bhv = b * 16 + (bn - 16) * 2 + hh;
      u16* dstp = vt + bhv * 131072L + (long)d * 2048 + keybase + kc;
      const u16* srcp = &Ts[(hh * 64 + d) * 136 + kc];
#pragma unroll
      for (int c = 0; c < 4; ++c)
        *reinterpret_cast<u16x8*>(dstp + c * 8) =
            *reinterpret_cast<const u16x8*>(srcp + c * 8);
    }
  }
}

// ---------------- FC GEMM: 128x64 tile, fp32 out, same swizzle ----------------
__global__ __launch_bounds__(256, 2) void gemm_fc(const u16* __restrict__ A,
                                                  const u16* __restrict__ W,
                                                  float* __restrict__ C) {
  constexpr int N = 1024, K = 1024;
  __shared__ __align__(16) u16 As[128 * 32];
  __shared__ __align__(16) u16 Bs[64 * 32];
  const int tid = threadIdx.x;
  const int lane = tid & 63;
  const int wid = tid >> 6;
  const int wm = wid >> 1, wn = wid & 1;
  const int l16 = lane & 15, g4 = lane >> 4;
  const int h4 = ((l16 >> 1) & 3) << 4;
  const long bm = blockIdx.x, bn = blockIdx.y;

  const int srow = tid >> 2;
  const int scolE = (((tid & 3) * 16) ^ (((srow >> 1) & 3) << 4)) >> 1;
  const u16* aA0 = A + (bm * 128 + srow) * (long)K + scolE;
  const u16* aA1 = aA0 + 64 * (long)K;
  const u16* aW0 = W + (bn * 64 + srow) * (long)K + scolE;

  f32x4 acc[4][2] = {};

  for (int kt = 0; kt < K; kt += 32) {
    __builtin_amdgcn_global_load_lds((AS1 void*)(aA0 + kt), (AS3 void*)(&As[tid * 8]), 16, 0, 0);
    __builtin_amdgcn_global_load_lds((AS1 void*)(aA1 + kt), (AS3 void*)(&As[2048 + tid * 8]), 16, 0, 0);
    __builtin_amdgcn_global_load_lds((AS1 void*)(aW0 + kt), (AS3 void*)(&Bs[tid * 8]), 16, 0, 0);
    __syncthreads();
    bf16x8 af[4], bfr[2];
#pragma unroll
    for (int m = 0; m < 4; ++m)
      af[m] = *reinterpret_cast<const bf16x8*>(
          &As[(wm * 64 + m * 16 + l16) * 32 + (((g4 * 16) ^ h4) >> 1)]);
#pragma unroll
    for (int n = 0; n < 2; ++n)
      bfr[n] = *reinterpret_cast<const bf16x8*>(
          &Bs[(wn * 32 + n * 16 + l16) * 32 + (((g4 * 16) ^ h4) >> 1)]);
#pragma unroll
    for (int m = 0; m < 4; ++m)
#pragma unroll
      for (int n = 0; n < 2; ++n)
        acc[m][n] = __builtin_amdgcn_mfma_f32_16x16x32_bf16(af[m], bfr[n], acc[m][n], 0, 0, 0);
    __syncthreads();
  }

#pragma unroll
  for (int m = 0; m < 4; ++m)
#pragma unroll
    for (int n = 0; n < 2; ++n)
#pragma unroll
      for (int j = 0; j < 4; ++j) {
        long row = bm * 128 + wm * 64 + m * 16 + g4 * 4 + j;
        long col = bn * 64 + wn * 32 + n * 16 + l16;
        C[row * N + col] = acc[m][n][j];
      }
}

// ---- causal flash attention: 2x2 wave split (qh x kh), P stays in registers --------
// (r9/r15 structure + fast_exp2 -- best measured: ~39 us, MfmaUtil ~25%. Untouched.)
__global__ __launch_bounds__(256, 4) void attn_causal(const u16* __restrict__ Qb,
                                                      const u16* __restrict__ Kbf,
                                                      const u16* __restrict__ vt,
                                                      u16* __restrict__ o) {
  __shared__ __align__(16) u16 SMEM[16384];  // 32 KB: K dbuf (16 KB) + V dbuf (16 KB)

  const int tid = threadIdx.x, lane = tid & 63, wid = tid >> 6;
  const int l16 = lane & 15, g4 = lane >> 4;
  const int h8 = (l16 & 7) << 4;
  const int qh = wid & 1, kh = wid >> 1;

  const int f = blockIdx.x;
  const int xcd = f & 7;
  const int g = f >> 3;
  const int hb = g >> 5;
  const int w = g & 31;
  const int bh = xcd * 4 + hb;
  const int basei = (w & 1) ? (31 - (w >> 1)) : (w >> 1);
  const int it = (hb & 1) ? (31 - basei) : basei;  // q-tile index 0..31

  const long base = (long)(bh >> 4) * 2048 * 1024 + (bh & 15) * 64;
  const u16* qb = Qb + base;
  const u16* kb = Kbf + base;
  const u16* vtb = vt + (long)bh * 131072;

  // Q hoist: rows it*64 + qh*32 + qf*16 + l16 (B-operand of QK mfma32)
  bf16x8 qv[2][2];
#pragma unroll
  for (int qf = 0; qf < 2; ++qf) {
    const u16* qp = qb + ((long)it * 64 + qh * 32 + qf * 16 + l16) * 1024;
    qv[qf][0] = *reinterpret_cast<const bf16x8*>(qp + g4 * 8);
    qv[qf][1] = *reinterpret_cast<const bf16x8*>(qp + 32 + g4 * 8);
  }

  f32x4 acc[2][4] = {};  // [qf][db]: row q = qf*16+g4*4+j (local), col d = db*16+l16
  f32x4 lacc[2] = {};    // [qf]: l for q = qf*16+g4*4+j

  s16x4 ones4;
#pragma unroll
  for (int j = 0; j < 4; ++j) ones4[j] = (short)0x3F80;  // bf16 1.0

  const int krow = tid >> 3;                                      // 0..31
  const int scolE = (((tid & 7) * 16) ^ ((krow & 7) << 4)) >> 1;  // swizzled col (elems)

  auto stage_issue = [&](int buf, int kt) {
    u16* KB = SMEM + buf * 4096;
    u16* VB = SMEM + 8192 + buf * 4096;
    __builtin_amdgcn_global_load_lds((AS1 void*)(kb + (long)(kt * 64 + krow) * 1024 + scolE),
                                     (AS3 void*)(&KB[tid * 8]), 16, 0, 0);
    __builtin_amdgcn_global_load_lds((AS1 void*)(kb + (long)(kt * 64 + krow + 32) * 1024 + scolE),
                                     (AS3 void*)(&KB[2048 + tid * 8]), 16, 0, 0);
    __builtin_amdgcn_global_load_lds((AS1 void*)(vtb + (long)krow * 2048 + kt * 64 + scolE),
                                     (AS3 void*)(&VB[tid * 8]), 16, 0, 0);
    __builtin_amdgcn_global_load_lds((AS1 void*)(vtb + (long)(krow + 32) * 2048 + kt * 64 + scolE),
                                     (AS3 void*)(&VB[2048 + tid * 8]), 16, 0, 0);
  };

  auto tile_step = [&](int cur, bool diag) {
    if (diag && qh == 0 && kh == 1) return;  // fully masked sub-block (wave-uniform)
    const u16* KB = SMEM + cur * 4096;
    const u16* VB = SMEM + 8192 + cur * 4096;
    // K A-frags: rows = wave's keys kh*32 + kf*16 + l16
    bf16x8 kfr[2][2];
#pragma unroll
    for (int kf = 0; kf < 2; ++kf) {
      const int row = kh * 32 + kf * 16 + l16;
#pragma unroll
      for (int ck = 0; ck < 2; ++ck)
        kfr[kf][ck] = *reinterpret_cast<const bf16x8*>(
            &KB[row * 64 + (((ck * 64 + g4 * 16) ^ h8) >> 1)]);
    }
    // S^T[key][q]: lane holds q = l16, keys = kf*16 + g4*4 + j (within wave's 32)
    f32x4 s[2][2];
    __builtin_amdgcn_s_setprio(1);
#pragma unroll
    for (int kf = 0; kf < 2; ++kf)
#pragma unroll
      for (int qf = 0; qf < 2; ++qf) {
        f32x4 z = {0.f, 0.f, 0.f, 0.f};
        z = __builtin_amdgcn_mfma_f32_16x16x32_bf16(kfr[kf][0], qv[qf][0], z, 0, 0, 0);
        z = __builtin_amdgcn_mfma_f32_16x16x32_bf16(kfr[kf][1], qv[qf][1], z, 0, 0, 0);
        s[kf][qf] = z;
      }
    __builtin_amdgcn_s_setprio(0);
    if (diag) {
#pragma unroll
      for (int kf = 0; kf < 2; ++kf)
#pragma unroll
        for (int qf = 0; qf < 2; ++qf) {
          const int keyl = kh * 32 + kf * 16 + g4 * 4;
          const int ql = qh * 32 + qf * 16 + l16;
#pragma unroll
          for (int j = 0; j < 4; ++j)
            if (keyl + j > ql) s[kf][qf][j] = -3e38f;
        }
    }
    // exp2 + pack to PV A-frags (zero data movement)
    s16x4 pfr[2][2];
#pragma unroll
    for (int kf = 0; kf < 2; ++kf)
#pragma unroll
      for (int qf = 0; qf < 2; ++qf) {
        bf16x4 p;
#pragma unroll
        for (int j = 0; j < 4; ++j) p[j] = (__bf16)fast_exp2(s[kf][qf][j]);
        pfr[kf][qf] = __builtin_bit_cast(s16x4, p);
      }
    __builtin_amdgcn_s_setprio(1);
#pragma unroll
    for (int qf = 0; qf < 2; ++qf) {
      lacc[qf] = mfma16(pfr[0][qf], ones4, lacc[qf]);
      lacc[qf] = mfma16(pfr[1][qf], ones4, lacc[qf]);
    }
    // PV: B-frag = V^T at (row d = db*16+l16, keys kh*64+kf*32+g4*8 bytes)
#pragma unroll
    for (int db = 0; db < 4; ++db) {
      const int vrow = db * 16 + l16;
#pragma unroll
      for (int kf = 0; kf < 2; ++kf) {
        const u16x4 vv = *reinterpret_cast<const u16x4*>(
            &VB[vrow * 64 + (((kh * 64 + kf * 32 + g4 * 8) ^ h8) >> 1)]);
        const s16x4 vf = __builtin_bit_cast(s16x4, vv);
#pragma unroll
        for (int qf = 0; qf < 2; ++qf) acc[qf][db] = mfma16(pfr[kf][qf], vf, acc[qf][db]);
      }
    }
    __builtin_amdgcn_s_setprio(0);
  };

  stage_issue(0, 0);
  __syncthreads();

  for (int kt = 0; kt < it; ++kt) {
    const int cur = kt & 1;
    stage_issue(cur ^ 1, kt + 1);
    tile_step(cur, false);
    __syncthreads();
  }
  tile_step(it & 1, true);  // diagonal tile
  __syncthreads();          // tiles done; SMEM reused for combine

  // ---- combine the 2 kh-halves (additive thanks to static-max softmax) ----
  float* Ebuf = reinterpret_cast<float*>(SMEM);  // [2(qh)][32][68] f32 = 17408 B
  const int ebase = qh * 2176;
  if (kh == 1) {
#pragma unroll
    for (int qf = 0; qf < 2; ++qf) {
#pragma unroll
      for (int db = 0; db < 4; ++db)
#pragma unroll
        for (int j = 0; j < 4; ++j)
          Ebuf[ebase + (qf * 16 + g4 * 4 + j) * 68 + db * 16 + l16] = acc[qf][db][j];
      if (l16 == 0) {
#pragma unroll
        for (int j = 0; j < 4; ++j)
          Ebuf[ebase + (qf * 16 + g4 * 4 + j) * 68 + 64] = lacc[qf][j];
      }
    }
  }
  __syncthreads();
  if (kh == 0) {
    const long obase = (long)(bh >> 4) * 2048 * 1024 + (bh & 15) * 64;
#pragma unroll
    for (int qf = 0; qf < 2; ++qf) {
      float linv[4];
#pragma unroll
      for (int j = 0; j < 4; ++j) {
        const float lsum = lacc[qf][j] + Ebuf[ebase + (qf * 16 + g4 * 4 + j) * 68 + 64];
        linv[j] = 1.0f / lsum;
      }
#pragma unroll
      for (int db = 0; db < 4; ++db)
#pragma unroll
        for (int j = 0; j < 4; ++j) {
          const int row = qh * 32 + qf * 16 + g4 * 4 + j;
          const float v =
              acc[qf][db][j] + Ebuf[ebase + (qf * 16 + g4 * 4 + j) * 68 + db * 16 + l16];
          o[obase + ((long)it * 64 + row) * 1024 + db * 16 + l16] = f2bf(v * linv[j]);
        }
    }
  }
}

extern "C" void kernel_launch(void* const* d_in, const int* in_sizes, int n_in,
                              void* d_out, int out_size, void* d_ws, size_t ws_size,
                              hipStream_t stream) {
  const float* x = (const float*)d_in[0];
  // d_in[1] = mask (causal tril -- not needed)
  const float* w_qkv = (const float*)d_in[2];
  const float* w_fc = (const float*)d_in[3];
  const float* qw = (const float*)d_in[4];
  const float* kw = (const float*)d_in[5];
  // d_in[6] = subset_attention_size: with a causal mask the split is an identity.
  float* out = (float*)d_out;

  char* ws = (char*)d_ws;
  u16* xb    = (u16*)(ws);                   // 8 MB
  u16* wqkvb = (u16*)(ws + (8L << 20));      // 6 MB
  u16* wfcb  = (u16*)(ws + (14L << 20));     // 2 MB
  u16* Qb    = (u16*)(ws + (16L << 20));     // 8 MB
  u16* Kbf   = (u16*)(ws + (24L << 20));     // 8 MB
  u16* vt    = (u16*)(ws + (32L << 20));     // 8 MB
  u16* ob    = (u16*)(ws + (40L << 20));     // 8 MB

  cvt_all<<<8192, 256, 0, stream>>>(x, w_qkv, w_fc, xb, wqkvb, wfcb);
  gemm_qkv<<<dim3(32, 24), 256, 0, stream>>>(xb, wqkvb, Qb, Kbf, vt, qw, kw);
  attn_causal<<<1024, 256, 0, stream>>>(Qb, Kbf, vt, ob);
  gemm_fc<<<dim3(32, 16), 256, 0, stream>>>(ob, wfcb, out);
}

// Round 21
// 95.587 us; speedup vs baseline: 1.0555x; 1.0148x over previous
//
#include <hip/hip_runtime.h>

typedef __bf16 bf16x8 __attribute__((ext_vector_type(8)));
typedef __bf16 bf16x4 __attribute__((ext_vector_type(4)));
typedef float f32x4 __attribute__((ext_vector_type(4)));
typedef short s16x4 __attribute__((ext_vector_type(4)));
typedef unsigned short u16;
typedef unsigned int u32;
typedef unsigned short u16x4 __attribute__((ext_vector_type(4)));
typedef unsigned short u16x8 __attribute__((ext_vector_type(8)));

#define AS1 __attribute__((address_space(1)))
#define AS3 __attribute__((address_space(3)))

__device__ __forceinline__ u16 f2bf(float f) {
  unsigned u = __builtin_bit_cast(unsigned, f);
  u += 0x7fffu + ((u >> 16) & 1u);
  return (u16)(u >> 16);
}

__device__ __forceinline__ float fast_exp2(float x) {
#if __has_builtin(__builtin_amdgcn_exp2f)
  return __builtin_amdgcn_exp2f(x);  // bare v_exp_f32
#else
  return exp2f(x);
#endif
}

__device__ __forceinline__ f32x4 mfma16(s16x4 a, s16x4 b, f32x4 c) {
#if __has_builtin(__builtin_amdgcn_mfma_f32_16x16x16bf16_1k)
  return __builtin_amdgcn_mfma_f32_16x16x16bf16_1k(a, b, c, 0, 0, 0);
#else
  asm("v_mfma_f32_16x16x16_bf16 %0, %1, %2, %0" : "+v"(c) : "v"(a), "v"(b));
  return c;
#endif
}

// ---------------- fp32 -> bf16 convert (x, w_qkv, w_fc fused) ----------------
__global__ __launch_bounds__(256) void cvt_all(const float* __restrict__ x,
                                               const float* __restrict__ wq,
                                               const float* __restrict__ wf,
                                               u16* __restrict__ xb, u16* __restrict__ wqb,
                                               u16* __restrict__ wfb) {
  long i = ((long)blockIdx.x * 256 + threadIdx.x) * 4;
  const float* src;
  u16* dst;
  long off;
  if (i < 4194304L) {
    src = x; dst = xb; off = i;
  } else if (i < 7340032L) {
    src = wq; dst = wqb; off = i - 4194304L;
  } else {
    src = wf; dst = wfb; off = i - 7340032L;
  }
  float4 v = *reinterpret_cast<const float4*>(src + off);
  u16x4 o;
  o.x = f2bf(v.x); o.y = f2bf(v.y); o.z = f2bf(v.z); o.w = f2bf(v.w);
  *reinterpret_cast<u16x4*>(dst + off) = o;
}

// -------- QKV GEMM: X[4096][1024] * W[3072][1024]^T, RMS fused, split outputs --------
// (r20: BK=32 single-buffered + 64B-row XOR swizzle ((row>>1)&3)<<4.)
__global__ __launch_bounds__(256, 2) void gemm_qkv(const u16* __restrict__ A,
                                                   const u16* __restrict__ W,
                                                   u16* __restrict__ Qb,
                                                   u16* __restrict__ Kbf,
                                                   u16* __restrict__ vt,
                                                   const float* __restrict__ qw,
                                                   const float* __restrict__ kw) {
  constexpr int K = 1024;
  __shared__ __align__(16) u16 As[128 * 32];
  __shared__ __align__(16) u16 Bs[128 * 32];
  __shared__ __align__(16) u16 Ts[128 * 136];  // V transpose scratch (34 KB)
  const int tid = threadIdx.x;
  const int lane = tid & 63;
  const int wid = tid >> 6;
  const int wm = wid >> 1, wn = wid & 1;
  const int l16 = lane & 15, g4 = lane >> 4;
  const int h4 = ((l16 >> 1) & 3) << 4;  // read-side XOR for rows == l16 (mod 16)
  const long bm = blockIdx.x, bn = blockIdx.y;

  const int srow = tid >> 2;                                          // 0..63
  const int scolE = (((tid & 3) * 16) ^ (((srow >> 1) & 3) << 4)) >> 1;  // swizzled src col
  const u16* aA0 = A + (bm * 128 + srow) * (long)K + scolE;
  const u16* aA1 = aA0 + 64 * (long)K;
  const u16* aW0 = W + (bn * 128 + srow) * (long)K + scolE;
  const u16* aW1 = aW0 + 64 * (long)K;

  f32x4 acc[4][4] = {};

  for (int kt = 0; kt < K; kt += 32) {
    __builtin_amdgcn_global_load_lds((AS1 void*)(aA0 + kt), (AS3 void*)(&As[tid * 8]), 16, 0, 0);
    __builtin_amdgcn_global_load_lds((AS1 void*)(aA1 + kt), (AS3 void*)(&As[2048 + tid * 8]), 16, 0, 0);
    __builtin_amdgcn_global_load_lds((AS1 void*)(aW0 + kt), (AS3 void*)(&Bs[tid * 8]), 16, 0, 0);
    __builtin_amdgcn_global_load_lds((AS1 void*)(aW1 + kt), (AS3 void*)(&Bs[2048 + tid * 8]), 16, 0, 0);
    __syncthreads();
    bf16x8 af[4], bfr[4];
#pragma unroll
    for (int m = 0; m < 4; ++m)
      af[m] = *reinterpret_cast<const bf16x8*>(
          &As[(wm * 64 + m * 16 + l16) * 32 + (((g4 * 16) ^ h4) >> 1)]);
#pragma unroll
    for (int n = 0; n < 4; ++n)
      bfr[n] = *reinterpret_cast<const bf16x8*>(
          &Bs[(wn * 64 + n * 16 + l16) * 32 + (((g4 * 16) ^ h4) >> 1)]);
#pragma unroll
    for (int m = 0; m < 4; ++m)
#pragma unroll
      for (int n = 0; n < 4; ++n)
        acc[m][n] = __builtin_amdgcn_mfma_f32_16x16x32_bf16(af[m], bfr[n], acc[m][n], 0, 0, 0);
    __syncthreads();
  }

  if (bn < 16) {
    // fused per-head RMSNorm for q (with attn scale) and k
    const float qscale = 0.18033688011112042f;  // 0.125 * log2(e)
    const float* w = (bn < 8) ? qw : kw;
    const float ws = (bn < 8) ? qscale : 1.0f;
    float wv[4];
#pragma unroll
    for (int n = 0; n < 4; ++n) wv[n] = w[n * 16 + l16] * ws;
#pragma unroll
    for (int m = 0; m < 4; ++m) {
#pragma unroll
      for (int j = 0; j < 4; ++j) {
        float ss = 0.f;
#pragma unroll
        for (int n = 0; n < 4; ++n) ss = fmaf(acc[m][n][j], acc[m][n][j], ss);
        ss += __shfl_xor(ss, 1);
        ss += __shfl_xor(ss, 2);
        ss += __shfl_xor(ss, 4);
        ss += __shfl_xor(ss, 8);
        const float inv = rsqrtf(ss * (1.0f / 64.0f) + 1e-5f);
#pragma unroll
        for (int n = 0; n < 4; ++n) acc[m][n][j] *= inv * wv[n];
      }
    }
    u16* dst = (bn < 8) ? Qb : Kbf;
    const long cb = (bn < 8) ? bn : (bn - 8);
#pragma unroll
    for (int m = 0; m < 4; ++m)
#pragma unroll
      for (int n = 0; n < 4; ++n)
#pragma unroll
        for (int j = 0; j < 4; ++j) {
          long row = bm * 128 + wm * 64 + m * 16 + g4 * 4 + j;
          long col = cb * 128 + wn * 64 + n * 16 + l16;
          dst[row * 1024 + col] = f2bf(acc[m][n][j]);
        }
  } else {
    // V: transpose via LDS, write vt[bh][d][key] coalesced
#pragma unroll
    for (int m = 0; m < 4; ++m)
#pragma unroll
      for (int n = 0; n < 4; ++n) {
        bf16x4 w4;
#pragma unroll
        for (int j = 0; j < 4; ++j) w4[j] = (__bf16)acc[m][n][j];
        const int lc = wn * 64 + n * 16 + l16;
        const int lr = wm * 64 + m * 16 + g4 * 4;
        *reinterpret_cast<bf16x4*>(&Ts[lc * 136 + lr]) = w4;
      }
    __syncthreads();
    const int b = (int)(bm >> 4);
    const int keybase = ((int)(bm & 15)) * 128;
#pragma unroll
    for (int u = 0; u < 2; ++u) {
      const int unit = u * 256 + tid;      // 0..511
      const int hh = unit >> 8;            // head half (2 heads per bn-block)
      const int d = (unit >> 2) & 63;
      const int kc = (unit & 3) * 32;
      const long bhv = b * 16 + (bn - 16) * 2 + hh;
      u16* dstp = vt + bhv * 131072L + (long)d * 2048 + keybase + kc;
      const u16* srcp = &Ts[(hh * 64 + d) * 136 + kc];
#pragma unroll
      for (int c = 0; c < 4; ++c)
        *reinterpret_cast<u16x8*>(dstp + c * 8) =
            *reinterpret_cast<const u16x8*>(srcp + c * 8);
    }
  }
}

// ---------------- FC GEMM: 128x64 tile, fp32 out, same swizzle ----------------
__global__ __launch_bounds__(256, 2) void gemm_fc(const u16* __restrict__ A,
                                                  const u16* __restrict__ W,
                                                  float* __restrict__ C) {
  constexpr int N = 1024, K = 1024;
  __shared__ __align__(16) u16 As[128 * 32];
  __shared__ __align__(16) u16 Bs[64 * 32];
  const int tid = threadIdx.x;
  const int lane = tid & 63;
  const int wid = tid >> 6;
  const int wm = wid >> 1, wn = wid & 1;
  const int l16 = lane & 15, g4 = lane >> 4;
  const int h4 = ((l16 >> 1) & 3) << 4;
  const long bm = blockIdx.x, bn = blockIdx.y;

  const int srow = tid >> 2;
  const int scolE = (((tid & 3) * 16) ^ (((srow >> 1) & 3) << 4)) >> 1;
  const u16* aA0 = A + (bm * 128 + srow) * (long)K + scolE;
  const u16* aA1 = aA0 + 64 * (long)K;
  const u16* aW0 = W + (bn * 64 + srow) * (long)K + scolE;

  f32x4 acc[4][2] = {};

  for (int kt = 0; kt < K; kt += 32) {
    __builtin_amdgcn_global_load_lds((AS1 void*)(aA0 + kt), (AS3 void*)(&As[tid * 8]), 16, 0, 0);
    __builtin_amdgcn_global_load_lds((AS1 void*)(aA1 + kt), (AS3 void*)(&As[2048 + tid * 8]), 16, 0, 0);
    __builtin_amdgcn_global_load_lds((AS1 void*)(aW0 + kt), (AS3 void*)(&Bs[tid * 8]), 16, 0, 0);
    __syncthreads();
    bf16x8 af[4], bfr[2];
#pragma unroll
    for (int m = 0; m < 4; ++m)
      af[m] = *reinterpret_cast<const bf16x8*>(
          &As[(wm * 64 + m * 16 + l16) * 32 + (((g4 * 16) ^ h4) >> 1)]);
#pragma unroll
    for (int n = 0; n < 2; ++n)
      bfr[n] = *reinterpret_cast<const bf16x8*>(
          &Bs[(wn * 32 + n * 16 + l16) * 32 + (((g4 * 16) ^ h4) >> 1)]);
#pragma unroll
    for (int m = 0; m < 4; ++m)
#pragma unroll
      for (int n = 0; n < 2; ++n)
        acc[m][n] = __builtin_amdgcn_mfma_f32_16x16x32_bf16(af[m], bfr[n], acc[m][n], 0, 0, 0);
    __syncthreads();
  }

#pragma unroll
  for (int m = 0; m < 4; ++m)
#pragma unroll
    for (int n = 0; n < 2; ++n)
#pragma unroll
      for (int j = 0; j < 4; ++j) {
        long row = bm * 128 + wm * 64 + m * 16 + g4 * 4 + j;
        long col = bn * 64 + wn * 32 + n * 16 + l16;
        C[row * N + col] = acc[m][n][j];
      }
}

// ---- causal flash attention: 2x2 wave split, P in registers, unroll-by-2 loop ------
// r20 structure; the K-loop is manually unrolled by 2 with LITERAL slot indices so
// every LDS address is a loop-invariant lane constant + compile-time offset (deletes
// the per-iteration cur*4096 address VALU on the dominant pipe).
__global__ __launch_bounds__(256, 4) void attn_causal(const u16* __restrict__ Qb,
                                                      const u16* __restrict__ Kbf,
                                                      const u16* __restrict__ vt,
                                                      u16* __restrict__ o) {
  __shared__ __align__(16) u16 SMEM[16384];  // K slots @0,@4096; V slots @8192,@12288

  const int tid = threadIdx.x, lane = tid & 63, wid = tid >> 6;
  const int l16 = lane & 15, g4 = lane >> 4;
  const int h8 = (l16 & 7) << 4;
  const int qh = wid & 1, kh = wid >> 1;

  const int f = blockIdx.x;
  const int xcd = f & 7;
  const int g = f >> 3;
  const int hb = g >> 5;
  const int w = g & 31;
  const int bh = xcd * 4 + hb;
  const int basei = (w & 1) ? (31 - (w >> 1)) : (w >> 1);
  const int it = (hb & 1) ? (31 - basei) : basei;  // q-tile index 0..31

  const long base = (long)(bh >> 4) * 2048 * 1024 + (bh & 15) * 64;
  const u16* qb = Qb + base;
  const u16* kb = Kbf + base;
  const u16* vtb = vt + (long)bh * 131072;

  // Q hoist: rows it*64 + qh*32 + qf*16 + l16 (B-operand of QK mfma32)
  bf16x8 qv[2][2];
#pragma unroll
  for (int qf = 0; qf < 2; ++qf) {
    const u16* qp = qb + ((long)it * 64 + qh * 32 + qf * 16 + l16) * 1024;
    qv[qf][0] = *reinterpret_cast<const bf16x8*>(qp + g4 * 8);
    qv[qf][1] = *reinterpret_cast<const bf16x8*>(qp + 32 + g4 * 8);
  }

  f32x4 acc[2][4] = {};  // [qf][db]: row q = qf*16+g4*4+j (local), col d = db*16+l16
  f32x4 lacc[2] = {};    // [qf]: l for q = qf*16+g4*4+j

  s16x4 ones4;
#pragma unroll
  for (int j = 0; j < 4; ++j) ones4[j] = (short)0x3F80;  // bf16 1.0

  const int krow = tid >> 3;                                      // 0..31
  const int scolE = (((tid & 7) * 16) ^ ((krow & 7) << 4)) >> 1;  // swizzled col (elems)

  auto stage_issue = [&](int buf, int kt) {
    u16* KB = SMEM + buf * 4096;
    u16* VB = SMEM + 8192 + buf * 4096;
    __builtin_amdgcn_global_load_lds((AS1 void*)(kb + (long)(kt * 64 + krow) * 1024 + scolE),
                                     (AS3 void*)(&KB[tid * 8]), 16, 0, 0);
    __builtin_amdgcn_global_load_lds((AS1 void*)(kb + (long)(kt * 64 + krow + 32) * 1024 + scolE),
                                     (AS3 void*)(&KB[2048 + tid * 8]), 16, 0, 0);
    __builtin_amdgcn_global_load_lds((AS1 void*)(vtb + (long)krow * 2048 + kt * 64 + scolE),
                                     (AS3 void*)(&VB[tid * 8]), 16, 0, 0);
    __builtin_amdgcn_global_load_lds((AS1 void*)(vtb + (long)(krow + 32) * 2048 + kt * 64 + scolE),
                                     (AS3 void*)(&VB[2048 + tid * 8]), 16, 0, 0);
  };

  auto tile_step = [&](int cur, bool diag) {
    if (diag && qh == 0 && kh == 1) return;  // fully masked sub-block (wave-uniform)
    const u16* KB = SMEM + cur * 4096;
    const u16* VB = SMEM + 8192 + cur * 4096;
    // K A-frags: rows = wave's keys kh*32 + kf*16 + l16
    bf16x8 kfr[2][2];
#pragma unroll
    for (int kf = 0; kf < 2; ++kf) {
      const int row = kh * 32 + kf * 16 + l16;
#pragma unroll
      for (int ck = 0; ck < 2; ++ck)
        kfr[kf][ck] = *reinterpret_cast<const bf16x8*>(
            &KB[row * 64 + (((ck * 64 + g4 * 16) ^ h8) >> 1)]);
    }
    // S^T[key][q]: lane holds q = l16, keys = kf*16 + g4*4 + j (within wave's 32)
    f32x4 s[2][2];
    __builtin_amdgcn_s_setprio(1);
#pragma unroll
    for (int kf = 0; kf < 2; ++kf)
#pragma unroll
      for (int qf = 0; qf < 2; ++qf) {
        f32x4 z = {0.f, 0.f, 0.f, 0.f};
        z = __builtin_amdgcn_mfma_f32_16x16x32_bf16(kfr[kf][0], qv[qf][0], z, 0, 0, 0);
        z = __builtin_amdgcn_mfma_f32_16x16x32_bf16(kfr[kf][1], qv[qf][1], z, 0, 0, 0);
        s[kf][qf] = z;
      }
    __builtin_amdgcn_s_setprio(0);
    if (diag) {
#pragma unroll
      for (int kf = 0; kf < 2; ++kf)
#pragma unroll
        for (int qf = 0; qf < 2; ++qf) {
          const int keyl = kh * 32 + kf * 16 + g4 * 4;
          const int ql = qh * 32 + qf * 16 + l16;
#pragma unroll
          for (int j = 0; j < 4; ++j)
            if (keyl + j > ql) s[kf][qf][j] = -3e38f;
        }
    }
    // exp2 + pack to PV A-frags (zero data movement)
    s16x4 pfr[2][2];
#pragma unroll
    for (int kf = 0; kf < 2; ++kf)
#pragma unroll
      for (int qf = 0; qf < 2; ++qf) {
        bf16x4 p;
#pragma unroll
        for (int j = 0; j < 4; ++j) p[j] = (__bf16)fast_exp2(s[kf][qf][j]);
        pfr[kf][qf] = __builtin_bit_cast(s16x4, p);
      }
    __builtin_amdgcn_s_setprio(1);
#pragma unroll
    for (int qf = 0; qf < 2; ++qf) {
      lacc[qf] = mfma16(pfr[0][qf], ones4, lacc[qf]);
      lacc[qf] = mfma16(pfr[1][qf], ones4, lacc[qf]);
    }
    // PV: B-frag = V^T at (row d = db*16+l16, keys kh*64+kf*32+g4*8 bytes)
#pragma unroll
    for (int db = 0; db < 4; ++db) {
      const int vrow = db * 16 + l16;
#pragma unroll
      for (int kf = 0; kf < 2; ++kf) {
        const u16x4 vv = *reinterpret_cast<const u16x4*>(
            &VB[vrow * 64 + (((kh * 64 + kf * 32 + g4 * 8) ^ h8) >> 1)]);
        const s16x4 vf = __builtin_bit_cast(s16x4, vv);
#pragma unroll
        for (int qf = 0; qf < 2; ++qf) acc[qf][db] = mfma16(pfr[kf][qf], vf, acc[qf][db]);
      }
    }
    __builtin_amdgcn_s_setprio(0);
  };

  stage_issue(0, 0);
  __syncthreads();

  // Manually unrolled by 2 with literal slot indices (compile-time LDS bases).
  int kt = 0;
  for (; kt + 1 < it; kt += 2) {
    stage_issue(1, kt + 1);
    tile_step(0, false);
    __syncthreads();
    stage_issue(0, kt + 2);
    tile_step(1, false);
    __syncthreads();
  }
  if (kt < it) {  // one remaining non-diagonal step (kt even here)
    stage_issue(1, kt + 1);
    tile_step(0, false);
    __syncthreads();
    kt++;
  }
  if ((kt & 1) == 0) tile_step(0, true);  // diagonal tile from slot kt&1
  else               tile_step(1, true);
  __syncthreads();  // tiles done; SMEM reused for combine

  // ---- combine the 2 kh-halves (additive thanks to static-max softmax) ----
  float* Ebuf = reinterpret_cast<float*>(SMEM);  // [2(qh)][32][68] f32 = 17408 B
  const int ebase = qh * 2176;
  if (kh == 1) {
#pragma unroll
    for (int qf = 0; qf < 2; ++qf) {
#pragma unroll
      for (int db = 0; db < 4; ++db)
#pragma unroll
        for (int j = 0; j < 4; ++j)
          Ebuf[ebase + (qf * 16 + g4 * 4 + j) * 68 + db * 16 + l16] = acc[qf][db][j];
      if (l16 == 0) {
#pragma unroll
        for (int j = 0; j < 4; ++j)
          Ebuf[ebase + (qf * 16 + g4 * 4 + j) * 68 + 64] = lacc[qf][j];
      }
    }
  }
  __syncthreads();
  if (kh == 0) {
    const long obase = (long)(bh >> 4) * 2048 * 1024 + (bh & 15) * 64;
#pragma unroll
    for (int qf = 0; qf < 2; ++qf) {
      float linv[4];
#pragma unroll
      for (int j = 0; j < 4; ++j) {
        const float lsum = lacc[qf][j] + Ebuf[ebase + (qf * 16 + g4 * 4 + j) * 68 + 64];
        linv[j] = 1.0f / lsum;
      }
#pragma unroll
      for (int db = 0; db < 4; ++db)
#pragma unroll
        for (int j = 0; j < 4; ++j) {
          const int row = qh * 32 + qf * 16 + g4 * 4 + j;
          const float v =
              acc[qf][db][j] + Ebuf[ebase + (qf * 16 + g4 * 4 + j) * 68 + db * 16 + l16];
          o[obase + ((long)it * 64 + row) * 1024 + db * 16 + l16] = f2bf(v * linv[j]);
        }
    }
  }
}

extern "C" void kernel_launch(void* const* d_in, const int* in_sizes, int n_in,
                              void* d_out, int out_size, void* d_ws, size_t ws_size,
                              hipStream_t stream) {
  const float* x = (const float*)d_in[0];
  // d_in[1] = mask (causal tril -- not needed)
  const float* w_qkv = (const float*)d_in[2];
  const float* w_fc = (const float*)d_in[3];
  const float* qw = (const float*)d_in[4];
  const float* kw = (const float*)d_in[5];
  // d_in[6] = subset_attention_size: with a causal mask the split is an identity.
  float* out = (float*)d_out;

  char* ws = (char*)d_ws;
  u16* xb    = (u16*)(ws);                   // 8 MB
  u16* wqkvb = (u16*)(ws + (8L << 20));      // 6 MB
  u16* wfcb  = (u16*)(ws + (14L << 20));     // 2 MB
  u16* Qb    = (u16*)(ws + (16L << 20));     // 8 MB
  u16* Kbf   = (u16*)(ws + (24L << 20));     // 8 MB
  u16* vt    = (u16*)(ws + (32L << 20));     // 8 MB
  u16* ob    = (u16*)(ws + (40L << 20));     // 8 MB

  cvt_all<<<8192, 256, 0, stream>>>(x, w_qkv, w_fc, xb, wqkvb, wfcb);
  gemm_qkv<<<dim3(32, 24), 256, 0, stream>>>(xb, wqkvb, Qb, Kbf, vt, qw, kw);
  attn_causal<<<1024, 256, 0, stream>>>(Qb, Kbf, vt, ob);
  gemm_fc<<<dim3(32, 16), 256, 0, stream>>>(ob, wfcb, out);
}